// Round 12
// baseline (31.163 us; speedup 1.0000x reference)
//
#include <hip/hip_runtime.h>
#include <hip/hip_bf16.h>

#define N_ATOMS 51200

// Output layout (flat floats, reference return order):
//   energy[512]@0, forces[153600]@512, stress[4608]@154112,
//   energy_uncert[512]@158720 (=0.6), force_uncert[153600]@159232 (computed),
//   stress_uncert[4608]@312832 (=0.1/16)
#define OUT_FUNC 159232

typedef __attribute__((ext_vector_type(4))) float f32x4;
typedef __attribute__((ext_vector_type(2))) unsigned u32x2;
typedef __attribute__((ext_vector_type(4))) unsigned u32x4;
typedef __attribute__((ext_vector_type(8))) short s16x8;

constexpr int BLK = 256;

__device__ __forceinline__ unsigned pack2(float lo, float hi) {
    return __builtin_amdgcn_perm(__float_as_uint(hi), __float_as_uint(lo), 0x07060302);
}
__device__ __forceinline__ s16x8 pack8(f32x4 lo, f32x4 hi) {
    union { u32x4 u; s16x8 s; } c;
    c.u.x = pack2(lo.x, lo.y); c.u.y = pack2(lo.z, lo.w);
    c.u.z = pack2(hi.x, hi.y); c.u.w = pack2(hi.z, hi.w);
    return c.s;
}
__device__ __forceinline__ short bftrunc(float x) {
    return (short)(__float_as_uint(x) >> 16);
}
__device__ __forceinline__ float silu_(float v) { return v / (1.0f + __expf(-v)); }

__global__ __launch_bounds__(BLK, 4) void funcert_kernel(
    const float* __restrict__ nf,
    const float* __restrict__ energy,
    const float* __restrict__ forces,
    const float* __restrict__ stress,
    const float* __restrict__ W1f, const float* __restrict__ b1f,
    const float* __restrict__ W2f, const float* __restrict__ b2f,
    const float* __restrict__ W3f, const float* __restrict__ b3f,
    float* __restrict__ out)
{
    const int t   = threadIdx.x;
    const int gid = blockIdx.x * BLK + t;

    __shared__ short Xq[2][64 * 64];   // 2 x 8 KB double-buffered quarter tiles
    __shared__ short H1s[64 * 64];     // 8 KB

    const int lane  = t & 63;
    const int w     = t >> 6;
    const int g     = lane >> 4;
    const int col   = lane & 15;
    const int abase = blockIdx.x * 64;
    const int ch    = w * 16 + col;

    const int rb  = t >> 4;
    const int f4c = t & 15;
    const float4* nfr = (const float4*)nf + (size_t)(abase + rb) * 96 + f4c;
    const int wbyte0 = rb * 128 + (f4c & 1) * 8;

    #define XQ_ISSUE(dst, qb)                                            \
        { _Pragma("unroll")                                              \
          for (int i = 0; i < 4; ++i)                                    \
              dst[i] = *(const f32x4*)(nfr + (size_t)i * 16 * 96 + (qb)); }

    #define XQ_STASH(buf, src)                                           \
        { _Pragma("unroll")                                              \
          for (int i = 0; i < 4; ++i) {                                  \
              const int r = rb + 16 * i;                                 \
              u32x2 bb;                                                  \
              bb.x = pack2(src[i].x, src[i].y);                          \
              bb.y = pack2(src[i].z, src[i].w);                          \
              *(u32x2*)((char*)(buf) + (wbyte0 + 2048 * i +              \
                        ((((f4c >> 1) ^ (r & 7))) << 4))) = bb;          \
          } }

    #define WQ_ISSUE(dst, q)                                             \
        { _Pragma("unroll")                                              \
          for (int ks2 = 0; ks2 < 2; ++ks2) {                            \
              const float* p = W1f + ch * 256 + (q) * 64 + ks2 * 32 + g * 8; \
              dst[2 * ks2]     = *(const f32x4*)p;                       \
              dst[2 * ks2 + 1] = *(const f32x4*)(p + 4);                 \
          } }

    #define Q_COMPUTE(buf, wf)                                           \
        { _Pragma("unroll")                                              \
          for (int mt = 0; mt < 4; ++mt) {                               \
              const int row = mt * 16 + col;                             \
              _Pragma("unroll")                                          \
              for (int ks2 = 0; ks2 < 2; ++ks2) {                        \
                  const int sl = (ks2 * 4 + g) ^ (row & 7);              \
                  const s16x8 af = *(const s16x8*)((buf) + row * 64 + sl * 8); \
                  acc[mt] = __builtin_amdgcn_mfma_f32_16x16x32_bf16(af, wf[ks2], acc[mt], 0, 0, 0); \
              } } }

    // DIAGNOSTIC: 3 identical reps over the SAME tile (idempotent).
    // Reps 2-3 are cache-warm -> discriminates delivery-bound vs structure-bound,
    // and lifts the kernel above the 46us memsets so rocprof top-5 shows it.
    #pragma unroll 1
    for (int rep = 0; rep < 3; ++rep) {

    f32x4 xa[4], xb[4], wv[4];
    s16x8 wf[2];
    f32x4 acc[4];
    #pragma unroll
    for (int mt = 0; mt < 4; ++mt) acc[mt] = (f32x4){0.f, 0.f, 0.f, 0.f};

    XQ_ISSUE(xa, 0);          // XQ0
    XQ_ISSUE(xb, 16);         // XQ1
    WQ_ISSUE(wv, 0);          // WQ0

    if (rep == 0 && gid < 40960) {
        f32x4 v; int o = gid;
        if      (gid < 128)   { v = ((const f32x4*)energy)[gid]; }
        else if (gid < 38528) { v = ((const f32x4*)forces)[gid - 128]; }
        else if (gid < 39680) { v = ((const f32x4*)stress)[gid - 38528]; }
        else if (gid < 39808) { v = (f32x4){0.6f, 0.6f, 0.6f, 0.6f}; }
        else { v = (f32x4){0.00625f, 0.00625f, 0.00625f, 0.00625f}; o = gid + 38400; }
        ((f32x4*)out)[o] = v;
    }
    const float b1v = b1f[ch];

    wf[0] = pack8(wv[0], wv[1]); wf[1] = pack8(wv[2], wv[3]);
    XQ_STASH(Xq[0], xa);
    __syncthreads();                     // buf0 ready
    XQ_ISSUE(xa, 64);                    // XQ2
    WQ_ISSUE(wv, 1);                     // WQ1
    Q_COMPUTE(Xq[0], wf);
    __syncthreads();

    wf[0] = pack8(wv[0], wv[1]); wf[1] = pack8(wv[2], wv[3]);
    XQ_STASH(Xq[1], xb);
    __syncthreads();                     // buf1 ready
    XQ_ISSUE(xb, 80);                    // XQ3
    WQ_ISSUE(wv, 2);                     // WQ2
    Q_COMPUTE(Xq[1], wf);
    __syncthreads();

    wf[0] = pack8(wv[0], wv[1]); wf[1] = pack8(wv[2], wv[3]);
    XQ_STASH(Xq[0], xa);
    __syncthreads();                     // buf0 ready
    WQ_ISSUE(wv, 3);                     // WQ3
    Q_COMPUTE(Xq[0], wf);
    __syncthreads();

    wf[0] = pack8(wv[0], wv[1]); wf[1] = pack8(wv[2], wv[3]);
    XQ_STASH(Xq[1], xb);
    __syncthreads();                     // buf1 ready
    Q_COMPUTE(Xq[1], wf);

    #pragma unroll
    for (int mt = 0; mt < 4; ++mt) {
        #pragma unroll
        for (int r = 0; r < 4; ++r) {
            const int atom = mt * 16 + g * 4 + r;
            H1s[atom * 64 + ch] = bftrunc(silu_(acc[mt][r] + b1v));
        }
    }
    __syncthreads();

    s16x8 w2frag[2];
    #pragma unroll
    for (int ks = 0; ks < 2; ++ks) {
        const float* p = W2f + col * 64 + ks * 32 + g * 8;
        w2frag[ks] = pack8(*(const f32x4*)p, *(const f32x4*)(p + 4));
    }
    const int arow = w * 16 + col;
    f32x4 a2 = {0.f, 0.f, 0.f, 0.f};
    #pragma unroll
    for (int ks = 0; ks < 2; ++ks) {
        const s16x8 af = *(const s16x8*)(H1s + arow * 64 + ks * 32 + g * 8);
        a2 = __builtin_amdgcn_mfma_f32_16x16x32_bf16(af, w2frag[ks], a2, 0, 0, 0);
    }

    const float b2v = b2f[col];
    const float w3v = W3f[col];
    float y[4];
    #pragma unroll
    for (int r = 0; r < 4; ++r)
        y[r] = silu_(a2[r] + b2v) * w3v;
    #pragma unroll
    for (int m = 1; m < 16; m <<= 1) {
        #pragma unroll
        for (int r = 0; r < 4; ++r)
            y[r] += __shfl_xor(y[r], m, 64);
    }
    const float b3v = b3f[0];
    float fu[4];
    #pragma unroll
    for (int r = 0; r < 4; ++r)
        fu[r] = __expf(y[r] + b3v) * 0.1f;

    if (col < 12) {
        const int a_ = col / 3, c = col - a_ * 3;
        const float v = (a_ == 0) ? fu[0] : (a_ == 1) ? fu[1] : (a_ == 2) ? fu[2] : fu[3];
        const int atom = w * 16 + g * 4 + a_;
        out[OUT_FUNC + 3 * (abase + atom) + c] = v;
    }

    __syncthreads();   // isolate reps (H1s/Xq reuse)
    }  // rep
}

extern "C" void kernel_launch(void* const* d_in, const int* in_sizes, int n_in,
                              void* d_out, int out_size, void* d_ws, size_t ws_size,
                              hipStream_t stream) {
    const float* nf     = (const float*)d_in[0];
    const float* energy = (const float*)d_in[1];
    const float* forces = (const float*)d_in[2];
    const float* stress = (const float*)d_in[3];
    const float* W1f    = (const float*)d_in[10];
    const float* b1f    = (const float*)d_in[11];
    const float* W2f    = (const float*)d_in[12];
    const float* b2f    = (const float*)d_in[13];
    const float* W3f    = (const float*)d_in[14];
    const float* b3f    = (const float*)d_in[15];
    float* out = (float*)d_out;

    dim3 grid(N_ATOMS / 64);   // 800 blocks
    funcert_kernel<<<grid, BLK, 0, stream>>>(nf, energy, forces, stress,
                                             W1f, b1f, W2f, b2f, W3f, b3f, out);
}

// Round 13
// 20.687 us; speedup vs baseline: 1.5065x; 1.5065x over previous
//
#include <hip/hip_runtime.h>
#include <hip/hip_bf16.h>

#define N_ATOMS 51200

// Output layout (flat floats, reference return order):
//   energy[512]@0, forces[153600]@512, stress[4608]@154112,
//   energy_uncert[512]@158720 (=0.6), force_uncert[153600]@159232 (computed),
//   stress_uncert[4608]@312832 (=0.1/16)
#define OUT_FUNC 159232

typedef __attribute__((ext_vector_type(4))) float f32x4;
typedef __attribute__((ext_vector_type(2))) unsigned u32x2;
typedef __attribute__((ext_vector_type(4))) unsigned u32x4;
typedef __attribute__((ext_vector_type(8))) short s16x8;

constexpr int BLK = 256;

__device__ __forceinline__ unsigned pack2(float lo, float hi) {
    return __builtin_amdgcn_perm(__float_as_uint(hi), __float_as_uint(lo), 0x07060302);
}
__device__ __forceinline__ s16x8 pack8(f32x4 lo, f32x4 hi) {
    union { u32x4 u; s16x8 s; } c;
    c.u.x = pack2(lo.x, lo.y); c.u.y = pack2(lo.z, lo.w);
    c.u.z = pack2(hi.x, hi.y); c.u.w = pack2(hi.z, hi.w);
    return c.s;
}
__device__ __forceinline__ short bftrunc(float x) {
    return (short)(__float_as_uint(x) >> 16);
}
__device__ __forceinline__ float silu_(float v) { return v / (1.0f + __expf(-v)); }

__global__ __launch_bounds__(BLK, 4) void funcert_kernel(
    const float* __restrict__ nf,
    const float* __restrict__ energy,
    const float* __restrict__ forces,
    const float* __restrict__ stress,
    const float* __restrict__ W1f, const float* __restrict__ b1f,
    const float* __restrict__ W2f, const float* __restrict__ b2f,
    const float* __restrict__ W3f, const float* __restrict__ b3f,
    float* __restrict__ out)
{
    const int t   = threadIdx.x;
    const int gid = blockIdx.x * BLK + t;

    __shared__ short Xq[2][64 * 64];   // 2 x 8 KB double-buffered quarter tiles
    __shared__ short H1s[64 * 64];     // 8 KB

    const int lane  = t & 63;
    const int w     = t >> 6;
    const int g     = lane >> 4;
    const int col   = lane & 15;
    const int abase = blockIdx.x * 64;
    const int ch    = w * 16 + col;

    const int rb  = t >> 4;
    const int f4c = t & 15;
    const float4* nfr = (const float4*)nf + (size_t)(abase + rb) * 96 + f4c;
    const int wbyte0 = rb * 128 + (f4c & 1) * 8;

    #define XQ_ISSUE(dst, qb)                                            \
        { _Pragma("unroll")                                              \
          for (int i = 0; i < 4; ++i)                                    \
              dst[i] = *(const f32x4*)(nfr + (size_t)i * 16 * 96 + (qb)); }

    #define XQ_STASH(buf, src)                                           \
        { _Pragma("unroll")                                              \
          for (int i = 0; i < 4; ++i) {                                  \
              const int r = rb + 16 * i;                                 \
              u32x2 bb;                                                  \
              bb.x = pack2(src[i].x, src[i].y);                          \
              bb.y = pack2(src[i].z, src[i].w);                          \
              *(u32x2*)((char*)(buf) + (wbyte0 + 2048 * i +              \
                        ((((f4c >> 1) ^ (r & 7))) << 4))) = bb;          \
          } }

    #define WQ_ISSUE(dst, q)                                             \
        { _Pragma("unroll")                                              \
          for (int ks2 = 0; ks2 < 2; ++ks2) {                            \
              const float* p = W1f + ch * 256 + (q) * 64 + ks2 * 32 + g * 8; \
              dst[2 * ks2]     = *(const f32x4*)p;                       \
              dst[2 * ks2 + 1] = *(const f32x4*)(p + 4);                 \
          } }

    #define Q_COMPUTE(buf, wf)                                           \
        { _Pragma("unroll")                                              \
          for (int mt = 0; mt < 4; ++mt) {                               \
              const int row = mt * 16 + col;                             \
              _Pragma("unroll")                                          \
              for (int ks2 = 0; ks2 < 2; ++ks2) {                        \
                  const int sl = (ks2 * 4 + g) ^ (row & 7);              \
                  const s16x8 af = *(const s16x8*)((buf) + row * 64 + sl * 8); \
                  acc[mt] = __builtin_amdgcn_mfma_f32_16x16x32_bf16(af, wf[ks2], acc[mt], 0, 0, 0); \
              } } }

    // ---- passthrough copy: LOAD issued FIRST (oldest in VMEM queue);
    //      store deferred to the very end so it never forces vmcnt(0) early ----
    f32x4 cv = {0.f, 0.f, 0.f, 0.f}; int co = -1;
    if (gid < 40960) {
        co = gid;
        if      (gid < 128)   { cv = ((const f32x4*)energy)[gid]; }
        else if (gid < 38528) { cv = ((const f32x4*)forces)[gid - 128]; }
        else if (gid < 39680) { cv = ((const f32x4*)stress)[gid - 38528]; }
        else if (gid < 39808) { cv = (f32x4){0.6f, 0.6f, 0.6f, 0.6f}; }
        else { cv = (f32x4){0.00625f, 0.00625f, 0.00625f, 0.00625f}; co = gid + 38400; }
    }

    // ---- prologue: W0 first (consumed first), then 3 quarters of X ----
    f32x4 wv[4];
    WQ_ISSUE(wv, 0);                     // WQ0  (oldest after copy load)
    const float b1v = b1f[ch];
    f32x4 xa[4], xb[4], xc[4];
    XQ_ISSUE(xa, 0);                     // XQ0
    XQ_ISSUE(xb, 16);                    // XQ1
    XQ_ISSUE(xc, 64);                    // XQ2

    f32x4 acc[4];
    #pragma unroll
    for (int mt = 0; mt < 4; ++mt) acc[mt] = (f32x4){0.f, 0.f, 0.f, 0.f};
    s16x8 wf[2];

    // ---- Q0 ----
    wf[0] = pack8(wv[0], wv[1]); wf[1] = pack8(wv[2], wv[3]);  // waits WQ0 only
    XQ_STASH(Xq[0], xa);                 // waits XQ0 only (counted vmcnt)
    __syncthreads();                     // buf0 ready
    WQ_ISSUE(wv, 1);                     // WQ1 BEFORE XQ3: pack(wv1) won't drain xa3
    XQ_ISSUE(xa, 80);                    // XQ3
    Q_COMPUTE(Xq[0], wf);
    __syncthreads();

    // ---- Q1 ----
    wf[0] = pack8(wv[0], wv[1]); wf[1] = pack8(wv[2], wv[3]);  // drains xb,xc (needed soon)
    XQ_STASH(Xq[1], xb);
    __syncthreads();                     // buf1 ready
    WQ_ISSUE(wv, 2);                     // WQ2
    Q_COMPUTE(Xq[1], wf);
    __syncthreads();

    // ---- Q2 ----
    wf[0] = pack8(wv[0], wv[1]); wf[1] = pack8(wv[2], wv[3]);
    XQ_STASH(Xq[0], xc);
    __syncthreads();                     // buf0 ready
    WQ_ISSUE(wv, 3);                     // WQ3
    Q_COMPUTE(Xq[0], wf);
    __syncthreads();

    // ---- Q3 ----
    wf[0] = pack8(wv[0], wv[1]); wf[1] = pack8(wv[2], wv[3]);
    XQ_STASH(Xq[1], xa);
    __syncthreads();                     // buf1 ready
    Q_COMPUTE(Xq[1], wf);

    // ---- bias + silu -> h1 ----
    #pragma unroll
    for (int mt = 0; mt < 4; ++mt) {
        #pragma unroll
        for (int r = 0; r < 4; ++r) {
            const int atom = mt * 16 + g * 4 + r;
            H1s[atom * 64 + ch] = bftrunc(silu_(acc[mt][r] + b1v));
        }
    }
    __syncthreads();

    // ---- L2: wave w -> atoms [16w,16w+16), 2 k-steps over 64 ch ----
    s16x8 w2frag[2];
    #pragma unroll
    for (int ks = 0; ks < 2; ++ks) {
        const float* p = W2f + col * 64 + ks * 32 + g * 8;   // B2[k][n] = W2f[n][k]
        w2frag[ks] = pack8(*(const f32x4*)p, *(const f32x4*)(p + 4));
    }
    const int arow = w * 16 + col;
    f32x4 a2 = {0.f, 0.f, 0.f, 0.f};
    #pragma unroll
    for (int ks = 0; ks < 2; ++ks) {
        const s16x8 af = *(const s16x8*)(H1s + arow * 64 + ks * 32 + g * 8);
        a2 = __builtin_amdgcn_mfma_f32_16x16x32_bf16(af, w2frag[ks], a2, 0, 0, 0);
    }

    // ---- h2 + L3 + exp ----
    const float b2v = b2f[col];
    const float w3v = W3f[col];
    float y[4];
    #pragma unroll
    for (int r = 0; r < 4; ++r)
        y[r] = silu_(a2[r] + b2v) * w3v;
    #pragma unroll
    for (int m = 1; m < 16; m <<= 1) {
        #pragma unroll
        for (int r = 0; r < 4; ++r)
            y[r] += __shfl_xor(y[r], m, 64);   // reduce over 16 cols
    }
    const float b3v = b3f[0];
    float fu[4];
    #pragma unroll
    for (int r = 0; r < 4; ++r)
        fu[r] = __expf(y[r] + b3v) * 0.1f;

    if (col < 12) {                            // 4 atoms x 3 comps per 16-lane group
        const int a_ = col / 3, c = col - a_ * 3;
        const float v = (a_ == 0) ? fu[0] : (a_ == 1) ? fu[1] : (a_ == 2) ? fu[2] : fu[3];
        const int atom = w * 16 + g * 4 + a_;
        out[OUT_FUNC + 3 * (abase + atom) + c] = v;
    }

    // ---- deferred passthrough store (data long since arrived; zero wait) ----
    if (co >= 0) ((f32x4*)out)[co] = cv;
}

extern "C" void kernel_launch(void* const* d_in, const int* in_sizes, int n_in,
                              void* d_out, int out_size, void* d_ws, size_t ws_size,
                              hipStream_t stream) {
    const float* nf     = (const float*)d_in[0];
    const float* energy = (const float*)d_in[1];
    const float* forces = (const float*)d_in[2];
    const float* stress = (const float*)d_in[3];
    const float* W1f    = (const float*)d_in[10];
    const float* b1f    = (const float*)d_in[11];
    const float* W2f    = (const float*)d_in[12];
    const float* b2f    = (const float*)d_in[13];
    const float* W3f    = (const float*)d_in[14];
    const float* b3f    = (const float*)d_in[15];
    float* out = (float*)d_out;

    dim3 grid(N_ATOMS / 64);   // 800 blocks
    funcert_kernel<<<grid, BLK, 0, stream>>>(nf, energy, forces, stress,
                                             W1f, b1f, W2f, b2f, W3f, b3f, out);
}